// Round 8
// baseline (94.588 us; speedup 1.0000x reference)
//
#include <hip/hip_runtime.h>
#include <math.h>

// SupConLoss reduced algebraically:
//   sum(sim)      = ||sum_i x_hat_i||^2 / T
//   sum(sim*mask) = sum_c ||S_c||^2 / T,  S_c = sum_{lab==c} x_hat_i
//   n_pos         = sum_c n_c^2
// O(N*H). Labels in [0,10). N=8192, H=768.
//
// R8: R7 structure (90.5us) + tail micro-opts:
//   - k2: 8-deep independent-load batching (strided partial reads are
//     L2/L3-scattered, ~200-900cyc; MLP depth is the only lever)
//   - k3: 384 threads (2 clean h-iterations, no wave tail)
// k1 frozen (R5 register-accumulator win + R7 8-deep phase B).
// Learned: R6 last-block-done fence handshake costs ~12us on non-coherent
// XCD L2s — extra dispatch is cheaper than device-scope fences.

#define NCLS 10
#define HDIM 768
#define HV4  (HDIM / 4)            // 192 float4 per row
#define CLS_FLOATS (NCLS * HDIM)   // 7680
#define PBLK 256                   // phase-1 blocks == partial count
#define RPB  32                    // rows per block = N / PBLK
#define PSLICES 8
#define NCHUNK (CLS_FLOATS / 256)  // 30

__global__ __launch_bounds__(768) void k1_fused(
    const float* __restrict__ x, const int* __restrict__ lab,
    float* __restrict__ partials) {
  __shared__ float srn[RPB];
  __shared__ int   slab[RPB];
  const int tid = threadIdx.x, lane = tid & 63, wave = tid >> 6;  // 12 waves
  const int row0 = blockIdx.x * RPB;
  const float4* __restrict__ x4 = (const float4*)x;

  // ---- phase A: row norms, wave-per-row ----
  for (int r = wave; r < RPB; r += 12) {
    const int row = row0 + r;
    const size_t b = (size_t)row * HV4;
    const float4 t0 = x4[b + lane];
    const float4 t1 = x4[b + 64 + lane];
    const float4 t2 = x4[b + 128 + lane];
    float ss = t0.x * t0.x + t0.y * t0.y + t0.z * t0.z + t0.w * t0.w +
               t1.x * t1.x + t1.y * t1.y + t1.z * t1.z + t1.w * t1.w +
               t2.x * t2.x + t2.y * t2.y + t2.z * t2.z + t2.w * t2.w;
#pragma unroll
    for (int off = 32; off >= 1; off >>= 1) ss += __shfl_xor(ss, off, 64);
    if (lane == 0) {
      srn[r] = 1.0f / fmaxf(sqrtf(ss), 1e-12f);  // F.normalize clamp
      slab[r] = lab[row];
    }
  }
  __syncthreads();

  // ---- phase B: one thread per h-column, register class accumulators ----
  float acc[NCLS];
#pragma unroll
  for (int c = 0; c < NCLS; ++c) acc[c] = 0.0f;

  for (int rb = 0; rb < RPB; rb += 8) {
    float v[8];
#pragma unroll
    for (int u = 0; u < 8; ++u)  // 8 independent L2-hit loads in flight
      v[u] = x[(size_t)(row0 + rb + u) * HDIM + tid];
#pragma unroll
    for (int u = 0; u < 8; ++u) {
      const float s = srn[rb + u];                                // broadcast
      const int c = __builtin_amdgcn_readfirstlane(slab[rb + u]); // uniform
      const float p = v[u] * s;
      switch (c) {  // scalar branch; acc[] stays in named VGPRs
        case 0: acc[0] += p; break;
        case 1: acc[1] += p; break;
        case 2: acc[2] += p; break;
        case 3: acc[3] += p; break;
        case 4: acc[4] += p; break;
        case 5: acc[5] += p; break;
        case 6: acc[6] += p; break;
        case 7: acc[7] += p; break;
        case 8: acc[8] += p; break;
        default: acc[9] += p; break;
      }
    }
  }

  float* __restrict__ outp = partials + (size_t)blockIdx.x * CLS_FLOATS;
#pragma unroll
  for (int c = 0; c < NCLS; ++c) outp[c * HDIM + tid] = acc[c];  // coalesced
}

// 240 blocks: (chunk, slice) sums its 32-partial slice over a 256-slot chunk.
__global__ __launch_bounds__(256) void k2_reduce(
    const float* __restrict__ partials, float* __restrict__ csum8) {
  const int chunk = blockIdx.x % NCHUNK;
  const int slice = blockIdx.x / NCHUNK;
  const int idx = chunk * 256 + threadIdx.x;
  const int p0 = slice * (PBLK / PSLICES);
  float s[8];
#pragma unroll
  for (int u = 0; u < 8; ++u) s[u] = 0.0f;
  for (int p = p0; p < p0 + PBLK / PSLICES; p += 8) {
#pragma unroll
    for (int u = 0; u < 8; ++u)  // 8 independent loads in flight
      s[u] += partials[(size_t)(p + u) * CLS_FLOATS + idx];
  }
  csum8[(size_t)slice * CLS_FLOATS + idx] =
      ((s[0] + s[1]) + (s[2] + s[3])) + ((s[4] + s[5]) + (s[6] + s[7]));
}

__global__ __launch_bounds__(384) void k3_final(
    const float* __restrict__ csum8, const int* __restrict__ lab,
    float* __restrict__ out, int N) {
  __shared__ int scnt[NCLS];
  __shared__ double r0s[6], r1s[6];
  const int tid = threadIdx.x, lane = tid & 63, wave = tid >> 6;  // 6 waves
  if (tid < NCLS) scnt[tid] = 0;
  __syncthreads();

  // label histogram via register counters
  int cnt[NCLS];
#pragma unroll
  for (int c = 0; c < NCLS; ++c) cnt[c] = 0;
  for (int i = tid; i < N; i += 384) {
    const int l = lab[i];
#pragma unroll
    for (int c = 0; c < NCLS; ++c) cnt[c] += (l == c);
  }
#pragma unroll
  for (int c = 0; c < NCLS; ++c) {
    int v = cnt[c];
#pragma unroll
    for (int off = 32; off >= 1; off >>= 1) v += __shfl_xor(v, off, 64);
    if (lane == 0) atomicAdd(&scnt[c], v);
  }

  double masked = 0.0, total = 0.0;
#pragma unroll
  for (int hi = 0; hi < 2; ++hi) {  // 768 = 2 * 384, clean
    const int h = hi * 384 + tid;
    double tv = 0.0;
#pragma unroll
    for (int c = 0; c < NCLS; ++c) {
      double sv = 0.0;
#pragma unroll
      for (int sl = 0; sl < PSLICES; ++sl)
        sv += (double)csum8[(size_t)sl * CLS_FLOATS + c * HDIM + h];
      masked += sv * sv;
      tv += sv;
    }
    total += tv * tv;
  }
#pragma unroll
  for (int off = 32; off >= 1; off >>= 1) {
    masked += __shfl_xor(masked, off, 64);
    total  += __shfl_xor(total,  off, 64);
  }
  if (lane == 0) { r0s[wave] = masked; r1s[wave] = total; }
  __syncthreads();
  if (tid == 0) {
    double m = 0.0, t = 0.0;
    for (int w = 0; w < 6; ++w) { m += r0s[w]; t += r1s[w]; }
    double n_pos = 0.0;
    for (int c = 0; c < NCLS; ++c) { const double cc = scnt[c]; n_pos += cc * cc; }
    const double T = 0.07;
    const double nn = (double)N * (double)N;
    const double pos_mean = m / (T * n_pos);
    const double neg_mean = (t - m) / (T * (nn - n_pos));
    const double d = neg_mean - pos_mean;
    out[0] = (float)(fmax(d, 0.0) + log1p(exp(-fabs(d))));  // logaddexp(0,d)
  }
}

extern "C" void kernel_launch(void* const* d_in, const int* in_sizes, int n_in,
                              void* d_out, int out_size, void* d_ws, size_t ws_size,
                              hipStream_t stream) {
  const float* x = (const float*)d_in[0];
  const int* lab = (const int*)d_in[1];
  const int N = in_sizes[1];  // 8192 = PBLK * RPB (fixed problem shape)

  float* partials = (float*)d_ws;                       // 256*7680 floats
  float* csum8 = partials + (size_t)PBLK * CLS_FLOATS;  // 8*7680 floats

  k1_fused<<<PBLK, HDIM, 0, stream>>>(x, lab, partials);
  k2_reduce<<<NCHUNK * PSLICES, 256, 0, stream>>>(partials, csum8);
  k3_final<<<1, 384, 0, stream>>>(csum8, lab, (float*)d_out, N);
}

// Round 9
// 90.108 us; speedup vs baseline: 1.0497x; 1.0497x over previous
//
#include <hip/hip_runtime.h>
#include <math.h>

// SupConLoss reduced algebraically:
//   sum(sim)      = ||sum_i x_hat_i||^2 / T
//   sum(sim*mask) = sum_c ||S_c||^2 / T,  S_c = sum_{lab==c} x_hat_i
//   n_pos         = sum_c n_c^2
// O(N*H). Labels in [0,10). N=8192, H=768.
//
// R9: exact revert to R7 (best measured: 90.53us). R8's k2/k3 tweaks were
// within the +-4us run-to-run noise band (harness fill nodes swing 42.5-45us
// each); locking in the best-known configuration.
// History: 119.9 (R1 LDS-atomic) -> 94.6 (R5 register-acc k1) -> 90.5 (R7
// 8-deep phase-B MLP + PSLICES=8). R4 cooperative fused = 184.7 (grid.sync
// cost); R6 last-block-done fence = 106.7 (device-scope fence across
// non-coherent XCD L2s costs more than a dispatch boundary).

#define NCLS 10
#define HDIM 768
#define HV4  (HDIM / 4)            // 192 float4 per row
#define CLS_FLOATS (NCLS * HDIM)   // 7680
#define PBLK 256                   // phase-1 blocks == partial count
#define RPB  32                    // rows per block = N / PBLK
#define PSLICES 8
#define NCHUNK (CLS_FLOATS / 256)  // 30

__global__ __launch_bounds__(768) void k1_fused(
    const float* __restrict__ x, const int* __restrict__ lab,
    float* __restrict__ partials) {
  __shared__ float srn[RPB];
  __shared__ int   slab[RPB];
  const int tid = threadIdx.x, lane = tid & 63, wave = tid >> 6;  // 12 waves
  const int row0 = blockIdx.x * RPB;
  const float4* __restrict__ x4 = (const float4*)x;

  // ---- phase A: row norms, wave-per-row ----
  for (int r = wave; r < RPB; r += 12) {
    const int row = row0 + r;
    const size_t b = (size_t)row * HV4;
    const float4 t0 = x4[b + lane];
    const float4 t1 = x4[b + 64 + lane];
    const float4 t2 = x4[b + 128 + lane];
    float ss = t0.x * t0.x + t0.y * t0.y + t0.z * t0.z + t0.w * t0.w +
               t1.x * t1.x + t1.y * t1.y + t1.z * t1.z + t1.w * t1.w +
               t2.x * t2.x + t2.y * t2.y + t2.z * t2.z + t2.w * t2.w;
#pragma unroll
    for (int off = 32; off >= 1; off >>= 1) ss += __shfl_xor(ss, off, 64);
    if (lane == 0) {
      srn[r] = 1.0f / fmaxf(sqrtf(ss), 1e-12f);  // F.normalize clamp
      slab[r] = lab[row];
    }
  }
  __syncthreads();

  // ---- phase B: one thread per h-column, register class accumulators ----
  float acc[NCLS];
#pragma unroll
  for (int c = 0; c < NCLS; ++c) acc[c] = 0.0f;

  for (int rb = 0; rb < RPB; rb += 8) {
    float v[8];
#pragma unroll
    for (int u = 0; u < 8; ++u)  // 8 independent L2-hit loads in flight
      v[u] = x[(size_t)(row0 + rb + u) * HDIM + tid];
#pragma unroll
    for (int u = 0; u < 8; ++u) {
      const float s = srn[rb + u];                                // broadcast
      const int c = __builtin_amdgcn_readfirstlane(slab[rb + u]); // uniform
      const float p = v[u] * s;
      switch (c) {  // scalar branch; acc[] stays in named VGPRs
        case 0: acc[0] += p; break;
        case 1: acc[1] += p; break;
        case 2: acc[2] += p; break;
        case 3: acc[3] += p; break;
        case 4: acc[4] += p; break;
        case 5: acc[5] += p; break;
        case 6: acc[6] += p; break;
        case 7: acc[7] += p; break;
        case 8: acc[8] += p; break;
        default: acc[9] += p; break;
      }
    }
  }

  float* __restrict__ outp = partials + (size_t)blockIdx.x * CLS_FLOATS;
#pragma unroll
  for (int c = 0; c < NCLS; ++c) outp[c * HDIM + tid] = acc[c];  // coalesced
}

// 240 blocks: (chunk, slice) sums its 32-partial slice over a 256-slot chunk.
__global__ __launch_bounds__(256) void k2_reduce(
    const float* __restrict__ partials, float* __restrict__ csum8) {
  const int chunk = blockIdx.x % NCHUNK;
  const int slice = blockIdx.x / NCHUNK;
  const int idx = chunk * 256 + threadIdx.x;
  const int p0 = slice * (PBLK / PSLICES);
  float s[4] = {0.f, 0.f, 0.f, 0.f};
  for (int p = p0; p < p0 + PBLK / PSLICES; p += 4) {
#pragma unroll
    for (int u = 0; u < 4; ++u)
      s[u] += partials[(size_t)(p + u) * CLS_FLOATS + idx];
  }
  csum8[(size_t)slice * CLS_FLOATS + idx] = (s[0] + s[1]) + (s[2] + s[3]);
}

__global__ __launch_bounds__(512) void k3_final(
    const float* __restrict__ csum8, const int* __restrict__ lab,
    float* __restrict__ out, int N) {
  __shared__ int scnt[NCLS];
  __shared__ double r0s[8], r1s[8];
  const int tid = threadIdx.x, lane = tid & 63, wave = tid >> 6;
  if (tid < NCLS) scnt[tid] = 0;
  __syncthreads();

  // label histogram via register counters
  int cnt[NCLS];
#pragma unroll
  for (int c = 0; c < NCLS; ++c) cnt[c] = 0;
  for (int i = tid; i < N; i += blockDim.x) {
    const int l = lab[i];
#pragma unroll
    for (int c = 0; c < NCLS; ++c) cnt[c] += (l == c);
  }
#pragma unroll
  for (int c = 0; c < NCLS; ++c) {
    int v = cnt[c];
#pragma unroll
    for (int off = 32; off >= 1; off >>= 1) v += __shfl_xor(v, off, 64);
    if (lane == 0) atomicAdd(&scnt[c], v);
  }

  double masked = 0.0, total = 0.0;
  for (int h = tid; h < HDIM; h += blockDim.x) {
    double tv = 0.0;
#pragma unroll
    for (int c = 0; c < NCLS; ++c) {
      double sv = 0.0;
#pragma unroll
      for (int sl = 0; sl < PSLICES; ++sl)
        sv += (double)csum8[(size_t)sl * CLS_FLOATS + c * HDIM + h];
      masked += sv * sv;
      tv += sv;
    }
    total += tv * tv;
  }
#pragma unroll
  for (int off = 32; off >= 1; off >>= 1) {
    masked += __shfl_xor(masked, off, 64);
    total  += __shfl_xor(total,  off, 64);
  }
  if (lane == 0) { r0s[wave] = masked; r1s[wave] = total; }
  __syncthreads();
  if (tid == 0) {
    double m = 0.0, t = 0.0;
    const int nw = blockDim.x >> 6;
    for (int w = 0; w < nw; ++w) { m += r0s[w]; t += r1s[w]; }
    double n_pos = 0.0;
    for (int c = 0; c < NCLS; ++c) { const double cc = scnt[c]; n_pos += cc * cc; }
    const double T = 0.07;
    const double nn = (double)N * (double)N;
    const double pos_mean = m / (T * n_pos);
    const double neg_mean = (t - m) / (T * (nn - n_pos));
    const double d = neg_mean - pos_mean;
    out[0] = (float)(fmax(d, 0.0) + log1p(exp(-fabs(d))));  // logaddexp(0,d)
  }
}

extern "C" void kernel_launch(void* const* d_in, const int* in_sizes, int n_in,
                              void* d_out, int out_size, void* d_ws, size_t ws_size,
                              hipStream_t stream) {
  const float* x = (const float*)d_in[0];
  const int* lab = (const int*)d_in[1];
  const int N = in_sizes[1];  // 8192 = PBLK * RPB (fixed problem shape)

  float* partials = (float*)d_ws;                       // 256*7680 floats
  float* csum8 = partials + (size_t)PBLK * CLS_FLOATS;  // 8*7680 floats

  k1_fused<<<PBLK, HDIM, 0, stream>>>(x, lab, partials);
  k2_reduce<<<NCHUNK * PSLICES, 256, 0, stream>>>(partials, csum8);
  k3_final<<<1, 512, 0, stream>>>(csum8, lab, (float*)d_out, N);
}